// Round 10
// baseline (1464.897 us; speedup 1.0000x reference)
//
#include <hip/hip_runtime.h>
#include <math.h>

// Problem constants (from reference setup_inputs)
#define BB      16384   // batch rows
#define DD      128     // embedding dim
#define VV      1000000 // vocab
#define NSAMP   8192    // NUM_SAMPLED
#define NSLICE  8       // candidate slices per row for the main pass
#define SLICE   (NSAMP / NSLICE)

__device__ __forceinline__ unsigned rotl32(unsigned x, unsigned r) {
    return (x << r) | (x >> (32u - r));
}

// ---------------------------------------------------------------------------
// XLA:CPU vectorized f32 exp (llvm_ir_runtime GenerateVF32Exp — the classic
// Cephes expansion). XLA emits plain fmul/fadd IR with fast-math OFF, so NO
// FMA contraction: every op is a separate IEEE f32 round. The pragma stops
// hipcc's default -ffp-contract from fusing the Horner chain.
// Domain here is [0, 13.816] -> fx in [0, 20]; clamps omitted (no-ops).
// ---------------------------------------------------------------------------
__device__ __forceinline__ float xla_expf(float x) {
#pragma clang fp contract(off)
    float fx = floorf(x * 1.44269504088896341f + 0.5f);  // LOG2EF, mul+add
    float tmp = fx * 0.693359375f;                        // cephes_exp_C1
    float z2  = fx * -2.12194440e-4f;                     // cephes_exp_C2
    float r = x - tmp;
    r = r - z2;
    float z = r * r;
    float y = 1.9875691500E-4f;
    y = y * r + 1.3981999507E-3f;
    y = y * r + 8.3334519073E-3f;
    y = y * r + 4.1665795894E-2f;
    y = y * r + 1.6666665459E-1f;
    y = y * r + 5.0000001201E-1f;
    y = y * z + r;
    y = y + 1.0f;
    int n = (int)fx;                                      // fx integral, >= 0
    float p2n = __builtin_bit_cast(float, (unsigned)((n + 127) << 23));
    return y * p2n;                                       // exact scaling
}

// f32-faithful logQ chain with correctly-rounded logs (replicates f32
// elementwise semantics incl. the cancellation quantization):
// lp = f32log( (f32log(id+2) - f32log(id+1)) / logr )
__device__ __forceinline__ float log_q32(float idf, float logr) {
    float l2 = (float)log((double)(idf + 2.0f));
    float l1 = (float)log((double)(idf + 1.0f));
    float q  = (l2 - l1) / logr;
    return (float)log((double)q);
}

// ---------------------------------------------------------------------------
// Kernel 0: detect target dtype (settled: int32, kept as a guard).
// ---------------------------------------------------------------------------
__global__ void detect_kernel(const unsigned* __restrict__ t,
                              unsigned* __restrict__ flag)
{
    __shared__ unsigned red[256];
    unsigned acc = 0;
    for (int i = threadIdx.x; i < BB / 2; i += 256) acc |= t[2 * i + 1];
    red[threadIdx.x] = acc;
    __syncthreads();
    for (int s = 128; s > 0; s >>= 1) {
        if ((int)threadIdx.x < s) red[threadIdx.x] |= red[threadIdx.x + s];
        __syncthreads();
    }
    if (threadIdx.x == 0) flag[0] = (red[0] == 0u) ? 1u : 0u;
}

__device__ __forceinline__ int load_target(const int* __restrict__ tgt,
                                           unsigned is64, int r)
{
    return is64 ? tgt[2 * r] : tgt[r];
}

// ---------------------------------------------------------------------------
// Kernel 1: partitionable threefry (confirmed): element i =
// threefry2x32(key=(0,1), counter=(0,i)), bits = out0^out1. Then
// u = bitcast((bits>>9)|0x3f800000) - 1.0f; t = u*logr (f32 mul);
// id = clip((int)floor(xla_expf(t)) - 1, 0, V-1);
// corr = bias[id] - (logns + logQ32(id)).
// ---------------------------------------------------------------------------
__global__ void sample_kernel(const float* __restrict__ bias,
                              int* __restrict__ ids,
                              float* __restrict__ corr,
                              float logr, float logns)
{
    int i = blockIdx.x * blockDim.x + threadIdx.x;
    if (i >= NSAMP) return;

    const unsigned k0 = 0u, k1 = 1u;
    const unsigned k2 = 0x1BD11BDAu ^ k0 ^ k1;
    unsigned x0 = 0u + k0;           // counter hi word + ks[0]
    unsigned x1 = (unsigned)i + k1;  // counter lo word + ks[1]

#define TFR(r) { x0 += x1; x1 = rotl32(x1, (r)); x1 ^= x0; }
    TFR(13) TFR(15) TFR(26) TFR(6)   x0 += k1; x1 += k2 + 1u;
    TFR(17) TFR(29) TFR(16) TFR(24)  x0 += k2; x1 += k0 + 2u;
    TFR(13) TFR(15) TFR(26) TFR(6)   x0 += k0; x1 += k1 + 3u;
    TFR(17) TFR(29) TFR(16) TFR(24)  x0 += k1; x1 += k2 + 4u;
    TFR(13) TFR(15) TFR(26) TFR(6)   x0 += k2; x1 += k0 + 5u;
#undef TFR

    unsigned bits = x0 ^ x1;         // partitionable 64->32 fold

    unsigned fb = (bits >> 9) | 0x3f800000u;
    float u = __builtin_bit_cast(float, fb) - 1.0f;
    float t = u * logr;                        // f32 mul, as in reference
    float ef = xla_expf(t);                    // XLA Cephes exp, no FMA
    int id = (int)floorf(ef) - 1;
    id = id < 0 ? 0 : (id > VV - 1 ? VV - 1 : id);

    float lp = log_q32((float)id, logr);
    ids[i]  = id;
    corr[i] = bias[id] - (logns + lp);
}

// ---------------------------------------------------------------------------
// Kernel 2: true logit per row: dot(x_b, emb[target_b]) + bias - (logns+logQ)
// ---------------------------------------------------------------------------
__global__ __launch_bounds__(256) void true_kernel(
    const float* __restrict__ x, const int* __restrict__ tgt,
    const float* __restrict__ emb, const float* __restrict__ bias,
    const unsigned* __restrict__ flag,
    float* __restrict__ tl, float logr, float logns)
{
    int r = blockIdx.x * 256 + threadIdx.x;
    if (r >= BB) return;
    int t = load_target(tgt, flag[0], r);
    const float4* xr = (const float4*)(x + (size_t)r * DD);
    const float4* wr = (const float4*)(emb + (size_t)t * DD);
    float a0 = 0.f, a1 = 0.f, a2 = 0.f, a3 = 0.f;
    #pragma unroll
    for (int k = 0; k < 32; k += 4) {
        float4 xv0 = xr[k],   wv0 = wr[k];
        float4 xv1 = xr[k+1], wv1 = wr[k+1];
        float4 xv2 = xr[k+2], wv2 = wr[k+2];
        float4 xv3 = xr[k+3], wv3 = wr[k+3];
        a0 += xv0.x*wv0.x + xv0.y*wv0.y + xv0.z*wv0.z + xv0.w*wv0.w;
        a1 += xv1.x*wv1.x + xv1.y*wv1.y + xv1.z*wv1.z + xv1.w*wv1.w;
        a2 += xv2.x*wv2.x + xv2.y*wv2.y + xv2.z*wv2.z + xv2.w*wv2.w;
        a3 += xv3.x*wv3.x + xv3.y*wv3.y + xv3.z*wv3.z + xv3.w*wv3.w;
    }
    float dot = (a0 + a1) + (a2 + a3);
    float lp  = log_q32((float)t, logr);
    tl[r] = dot + bias[t] - (logns + lp);
}

// ---------------------------------------------------------------------------
// Kernel 3: main pass. Thread-per-row, x row (128 f32) in VGPRs; block-y
// handles one slice of 1024 candidates with an online logsumexp. Candidate
// weight rows are wave-uniform loads (L2-resident, ~4 MB hot set).
// ---------------------------------------------------------------------------
__global__ __launch_bounds__(256, 2) void main_kernel(
    const float* __restrict__ x, const int* __restrict__ tgt,
    const float* __restrict__ emb,
    const int* __restrict__ ids, const float* __restrict__ corr,
    const unsigned* __restrict__ flag,
    float* __restrict__ pm, float* __restrict__ ps)
{
    int r = blockIdx.x * 256 + threadIdx.x;
    int s = blockIdx.y;
    if (r >= BB) return;

    float4 xr[32];
    const float4* xp = (const float4*)(x + (size_t)r * DD);
    #pragma unroll
    for (int k = 0; k < 32; k++) xr[k] = xp[k];

    int target = load_target(tgt, flag[0], r);
    float m = -1e29f, ss = 0.f;

    int j0 = s * SLICE;
    for (int j = j0; j < j0 + SLICE; j++) {
        int   id = ids[j];   // wave-uniform
        float c  = corr[j];
        const float4* w4 = (const float4*)(emb + (size_t)id * DD);
        float a0 = 0.f, a1 = 0.f, a2 = 0.f, a3 = 0.f;
        #pragma unroll
        for (int k = 0; k < 32; k += 4) {
            float4 w0 = w4[k], w1 = w4[k+1], w2 = w4[k+2], w3 = w4[k+3];
            a0 += xr[k].x*w0.x + xr[k].y*w0.y + xr[k].z*w0.z + xr[k].w*w0.w;
            a1 += xr[k+1].x*w1.x + xr[k+1].y*w1.y + xr[k+1].z*w1.z + xr[k+1].w*w1.w;
            a2 += xr[k+2].x*w2.x + xr[k+2].y*w2.y + xr[k+2].z*w2.z + xr[k+2].w*w2.w;
            a3 += xr[k+3].x*w3.x + xr[k+3].y*w3.y + xr[k+3].z*w3.z + xr[k+3].w*w3.w;
        }
        float l  = ((a0 + a1) + (a2 + a3)) + c;
        float lv = (id != target) ? l : -1e30f;   // hit exclusion (== ref's -1e9)
        float nm = fmaxf(m, lv);
        ss = ss * __expf(m - nm) + __expf(lv - nm);
        m = nm;
    }
    pm[(size_t)r * NSLICE + s] = m;
    ps[(size_t)r * NSLICE + s] = ss;
}

// ---------------------------------------------------------------------------
// Kernel 4: combine partial (m,s) across slices + true logit -> loss
// ---------------------------------------------------------------------------
__global__ __launch_bounds__(256) void combine_kernel(
    const float* __restrict__ tl,
    const float* __restrict__ pm, const float* __restrict__ ps,
    float* __restrict__ out)
{
    int r = blockIdx.x * 256 + threadIdx.x;
    if (r >= BB) return;
    float t = tl[r];
    float M = t;
    #pragma unroll
    for (int s = 0; s < NSLICE; s++) M = fmaxf(M, pm[(size_t)r * NSLICE + s]);
    float S = expf(t - M);
    #pragma unroll
    for (int s = 0; s < NSLICE; s++)
        S += ps[(size_t)r * NSLICE + s] * expf(pm[(size_t)r * NSLICE + s] - M);
    out[r] = M + logf(S) - t;
}

// ---------------------------------------------------------------------------
extern "C" void kernel_launch(void* const* d_in, const int* in_sizes, int n_in,
                              void* d_out, int out_size, void* d_ws, size_t ws_size,
                              hipStream_t stream)
{
    const float* x    = (const float*)d_in[0];   // [B, D] f32
    const int*   tgt  = (const int*)d_in[1];     // [B, 1] int32 (guarded)
    const float* emb  = (const float*)d_in[2];   // [V, D] f32
    const float* bias = (const float*)d_in[3];   // [V] f32
    float* out = (float*)d_out;                  // [B] f32

    char* w = (char*)d_ws;
    int*      ids  = (int*)w;                               // 8192 * 4
    float*    corr = (float*)(w + NSAMP * 4);               // 8192 * 4
    float*    tl   = (float*)(w + NSAMP * 8);               // 16384 * 4
    float*    pm   = (float*)(w + NSAMP * 8 + BB * 4);      // 16384*8 * 4
    float*    ps   = pm + (size_t)BB * NSLICE;              // 16384*8 * 4
    unsigned* flag = (unsigned*)(ps + (size_t)BB * NSLICE); // 1 * 4

    // Scalar constants: XLA constant-folds jnp.log of a scalar via
    // HloEvaluator -> std::log (glibc, CR); numpy scalar ufunc agrees.
    const float logr  = (float)log(1000001.0);   // log_range = f32 CR
    const float logns = (float)log(8192.0);      // log_ns    = f32 CR

    detect_kernel<<<dim3(1), dim3(256), 0, stream>>>((const unsigned*)tgt, flag);
    sample_kernel<<<dim3(NSAMP / 256), dim3(256), 0, stream>>>(
        bias, ids, corr, logr, logns);
    true_kernel<<<dim3(BB / 256), dim3(256), 0, stream>>>(
        x, tgt, emb, bias, flag, tl, logr, logns);
    main_kernel<<<dim3(BB / 256, NSLICE), dim3(256), 0, stream>>>(
        x, tgt, emb, ids, corr, flag, pm, ps);
    combine_kernel<<<dim3(BB / 256), dim3(256), 0, stream>>>(tl, pm, ps, out);
}

// Round 12
// 281.195 us; speedup vs baseline: 5.2095x; 5.2095x over previous
//
#include <hip/hip_runtime.h>
#include <math.h>

#define BB      16384   // batch rows
#define DD      128     // embedding dim
#define VV      1000000 // vocab
#define NSAMP   8192    // NUM_SAMPLED
#define NT      (NSAMP / 64)   // 128 N-tiles of 64 candidates

typedef __attribute__((ext_vector_type(8)))  unsigned short u16x8;
typedef __attribute__((ext_vector_type(8)))  __bf16         bf16x8;
typedef __attribute__((ext_vector_type(16))) float          f32x16;

__device__ __forceinline__ unsigned rotl32(unsigned x, unsigned r) {
    return (x << r) | (x >> (32u - r));
}

// RNE float -> bf16 (inputs are normal floats here)
__device__ __forceinline__ unsigned short bf16r(float v) {
    unsigned b = __builtin_bit_cast(unsigned, v);
    unsigned r = (b + 0x7fffu + ((b >> 16) & 1u)) >> 16;
    return (unsigned short)r;
}
__device__ __forceinline__ float bfval(unsigned short h) {
    return __builtin_bit_cast(float, (unsigned)h << 16);
}

// ---------------------------------------------------------------------------
// XLA:CPU vectorized f32 exp (Cephes, NO FMA — verified PASS in round 10).
// ---------------------------------------------------------------------------
__device__ __forceinline__ float xla_expf(float x) {
#pragma clang fp contract(off)
    float fx = floorf(x * 1.44269504088896341f + 0.5f);
    float tmp = fx * 0.693359375f;
    float z2  = fx * -2.12194440e-4f;
    float r = x - tmp;
    r = r - z2;
    float z = r * r;
    float y = 1.9875691500E-4f;
    y = y * r + 1.3981999507E-3f;
    y = y * r + 8.3334519073E-3f;
    y = y * r + 4.1665795894E-2f;
    y = y * r + 1.6666665459E-1f;
    y = y * r + 5.0000001201E-1f;
    y = y * z + r;
    y = y + 1.0f;
    int n = (int)fx;
    float p2n = __builtin_bit_cast(float, (unsigned)((n + 127) << 23));
    return y * p2n;
}

__device__ __forceinline__ float log_q32(float idf, float logr) {
    float l2 = (float)log((double)(idf + 2.0f));
    float l1 = (float)log((double)(idf + 1.0f));
    float q  = (l2 - l1) / logr;
    return (float)log((double)q);
}

// ---------------------------------------------------------------------------
__global__ void detect_kernel(const unsigned* __restrict__ t,
                              unsigned* __restrict__ flag)
{
    __shared__ unsigned red[256];
    unsigned acc = 0;
    for (int i = threadIdx.x; i < BB / 2; i += 256) acc |= t[2 * i + 1];
    red[threadIdx.x] = acc;
    __syncthreads();
    for (int s = 128; s > 0; s >>= 1) {
        if ((int)threadIdx.x < s) red[threadIdx.x] |= red[threadIdx.x + s];
        __syncthreads();
    }
    if (threadIdx.x == 0) flag[0] = (red[0] == 0u) ? 1u : 0u;
}

// ---------------------------------------------------------------------------
// sample: partitionable threefry + XLA Cephes exp (VERIFIED — unchanged)
// ---------------------------------------------------------------------------
__global__ void sample_kernel(const float* __restrict__ bias,
                              int* __restrict__ ids,
                              float* __restrict__ corr,
                              float logr, float logns)
{
    int i = blockIdx.x * blockDim.x + threadIdx.x;
    if (i >= NSAMP) return;

    const unsigned k0 = 0u, k1 = 1u;
    const unsigned k2 = 0x1BD11BDAu ^ k0 ^ k1;
    unsigned x0 = 0u + k0;
    unsigned x1 = (unsigned)i + k1;
#define TFR(r) { x0 += x1; x1 = rotl32(x1, (r)); x1 ^= x0; }
    TFR(13) TFR(15) TFR(26) TFR(6)   x0 += k1; x1 += k2 + 1u;
    TFR(17) TFR(29) TFR(16) TFR(24)  x0 += k2; x1 += k0 + 2u;
    TFR(13) TFR(15) TFR(26) TFR(6)   x0 += k0; x1 += k1 + 3u;
    TFR(17) TFR(29) TFR(16) TFR(24)  x0 += k1; x1 += k2 + 4u;
    TFR(13) TFR(15) TFR(26) TFR(6)   x0 += k2; x1 += k0 + 5u;
#undef TFR
    unsigned bits = x0 ^ x1;

    unsigned fb = (bits >> 9) | 0x3f800000u;
    float u = __builtin_bit_cast(float, fb) - 1.0f;
    float t = u * logr;
    float ef = xla_expf(t);
    int id = (int)floorf(ef) - 1;
    id = id < 0 ? 0 : (id > VV - 1 ? VV - 1 : id);

    float lp = log_q32((float)id, logr);
    ids[i]  = id;
    corr[i] = bias[id] - (logns + lp);
}

// ---------------------------------------------------------------------------
// wprep: gather sampled rows, split f32 -> bf16 hi + bf16 lo
// ---------------------------------------------------------------------------
__global__ __launch_bounds__(256) void wprep_kernel(
    const float* __restrict__ emb, const int* __restrict__ ids,
    unsigned short* __restrict__ Wh, unsigned short* __restrict__ Wl)
{
    int g = blockIdx.x * 256 + threadIdx.x;        // 0 .. 8192*128-1
    int row = g >> 7;
    int k   = g & 127;
    float v = emb[(size_t)ids[row] * DD + k];
    unsigned short h = bf16r(v);
    Wh[g] = h;
    Wl[g] = bf16r(v - bfval(h));
}

// ---------------------------------------------------------------------------
// true logit (VERIFIED — unchanged)
// ---------------------------------------------------------------------------
__global__ __launch_bounds__(256) void true_kernel(
    const float* __restrict__ x, const int* __restrict__ tgt,
    const float* __restrict__ emb, const float* __restrict__ bias,
    const unsigned* __restrict__ flag,
    float* __restrict__ tl, float logr, float logns)
{
    int r = blockIdx.x * 256 + threadIdx.x;
    if (r >= BB) return;
    int t = flag[0] ? tgt[2 * r] : tgt[r];
    const float4* xr = (const float4*)(x + (size_t)r * DD);
    const float4* wr = (const float4*)(emb + (size_t)t * DD);
    float a0 = 0.f, a1 = 0.f, a2 = 0.f, a3 = 0.f;
    #pragma unroll
    for (int k = 0; k < 32; k += 4) {
        float4 xv0 = xr[k],   wv0 = wr[k];
        float4 xv1 = xr[k+1], wv1 = wr[k+1];
        float4 xv2 = xr[k+2], wv2 = wr[k+2];
        float4 xv3 = xr[k+3], wv3 = wr[k+3];
        a0 += xv0.x*wv0.x + xv0.y*wv0.y + xv0.z*wv0.z + xv0.w*wv0.w;
        a1 += xv1.x*wv1.x + xv1.y*wv1.y + xv1.z*wv1.z + xv1.w*wv1.w;
        a2 += xv2.x*wv2.x + xv2.y*wv2.y + xv2.z*wv2.z + xv2.w*wv2.w;
        a3 += xv3.x*wv3.x + xv3.y*wv3.y + xv3.z*wv3.z + xv3.w*wv3.w;
    }
    float dot = (a0 + a1) + (a2 + a3);
    float lp  = log_q32((float)t, logr);
    tl[r] = dot + bias[t] - (logns + lp);
}

// ---------------------------------------------------------------------------
// Main GEMM: 64x64 block tile, 4 waves (2 row x 2 col), 32x32x16 bf16 MFMA,
// 3-way split (xh*wh + xl*wh + xh*wl), fixed-offset LSE (exp(l-60), no max),
// exact hit masking in-epilogue. W tiles double-buffered in LDS, XOR-swizzle.
// R11 bug fixed here: B-fragment LDS row must include the wave-column split
// (wc*32 + ln31), not ln31 alone.
// ---------------------------------------------------------------------------
__device__ __forceinline__ int swz(int row, int slot) {
    return row * 256 + ((slot ^ (row & 15)) << 4);
}

__global__ __launch_bounds__(256, 1) void gemm_kernel(
    const float* __restrict__ x, const int* __restrict__ tgt,
    const unsigned* __restrict__ flag,
    const unsigned short* __restrict__ Wh, const unsigned short* __restrict__ Wl,
    const int* __restrict__ ids, const float* __restrict__ corr,
    float* __restrict__ ps)
{
    __shared__ char lds[65536];   // 2 bufs x (Wh 16K + Wl 16K)

    const int tid  = threadIdx.x;
    const int lane = tid & 63;
    const int wid  = tid >> 6;
    const int wr   = wid >> 1, wc = wid & 1;
    const int half = lane >> 5, ln31 = lane & 31;
    const int m0   = blockIdx.x * 64;

    // ---- A fragments: 32 rows x 128 k, hi+lo, resident in VGPRs ----
    u16x8 ah[8], al[8];
    {
        const float* xr = x + (size_t)(m0 + wr * 32 + ln31) * DD;
        #pragma unroll
        for (int ks = 0; ks < 8; ks++) {
            const float4* p = (const float4*)(xr + ks * 16 + half * 8);
            float4 f0 = p[0], f1 = p[1];
            float v[8] = {f0.x, f0.y, f0.z, f0.w, f1.x, f1.y, f1.z, f1.w};
            u16x8 h, l;
            #pragma unroll
            for (int j = 0; j < 8; j++) {
                unsigned short hb = bf16r(v[j]);
                h[j] = hb;
                l[j] = bf16r(v[j] - bfval(hb));
            }
            ah[ks] = h; al[ks] = l;
        }
    }

    // ---- targets for this lane's 16 C rows ----
    const unsigned is64 = flag[0];
    int t16[16];
    #pragma unroll
    for (int i = 0; i < 16; i++) {
        int grow = m0 + wr * 32 + (i & 3) + 8 * (i >> 2) + 4 * half;
        t16[i] = is64 ? tgt[2 * grow] : tgt[grow];
    }

    float ss[16];
    #pragma unroll
    for (int i = 0; i < 16; i++) ss[i] = 0.f;

    const int srow = tid >> 2, s4 = (tid & 3) * 4;
    const int brow = wc * 32 + ln31;          // B row: THE R11 FIX

    // ---- prologue: stage tile 0 into buf 0 ----
    {
        const uint4* wh = (const uint4*)(Wh + (size_t)srow * DD);
        const uint4* wl = (const uint4*)(Wl + (size_t)srow * DD);
        #pragma unroll
        for (int k = 0; k < 4; k++) {
            uint4 a = wh[s4 + k], b = wl[s4 + k];
            *(uint4*)(lds + swz(srow, s4 + k))         = a;
            *(uint4*)(lds + 16384 + swz(srow, s4 + k)) = b;
        }
    }
    __syncthreads();

    for (int t = 0; t < NT; t++) {
        const int c = t & 1;
        // issue next-tile global loads early (hide under MFMA)
        uint4 ph[4], pl[4];
        const bool pf = (t + 1 < NT);
        if (pf) {
            const uint4* wh = (const uint4*)(Wh + (size_t)((t + 1) * 64 + srow) * DD);
            const uint4* wl = (const uint4*)(Wl + (size_t)((t + 1) * 64 + srow) * DD);
            #pragma unroll
            for (int k = 0; k < 4; k++) { ph[k] = wh[s4 + k]; pl[k] = wl[s4 + k]; }
        }

        // compute current tile
        const char* bh_base = lds + c * 32768;
        const char* bl_base = bh_base + 16384;
        f32x16 hh, lh2, hl;
        #pragma unroll
        for (int q = 0; q < 16; q++) { hh[q] = 0.f; lh2[q] = 0.f; hl[q] = 0.f; }

        #pragma unroll
        for (int ks = 0; ks < 8; ks++) {
            int off = swz(brow, ks * 2 + half);
            bf16x8 bh = __builtin_bit_cast(bf16x8, *(const uint4*)(bh_base + off));
            bf16x8 bl = __builtin_bit_cast(bf16x8, *(const uint4*)(bl_base + off));
            bf16x8 a_h = __builtin_bit_cast(bf16x8, ah[ks]);
            bf16x8 a_l = __builtin_bit_cast(bf16x8, al[ks]);
            hh  = __builtin_amdgcn_mfma_f32_32x32x16_bf16(a_h, bh, hh,  0, 0, 0);
            lh2 = __builtin_amdgcn_mfma_f32_32x32x16_bf16(a_l, bh, lh2, 0, 0, 0);
            hl  = __builtin_amdgcn_mfma_f32_32x32x16_bf16(a_h, bl, hl,  0, 0, 0);
        }

        // epilogue: logit = C + corr - 60; exact hit mask; accumulate exp
        const int j = t * 64 + wc * 32 + ln31;
        const float cc = corr[j] - 60.0f;
        const int idj = ids[j];
        #pragma unroll
        for (int i = 0; i < 16; i++) {
            float lt = hh[i] + lh2[i] + hl[i] + cc;
            float e = (idj == t16[i]) ? 0.0f : __expf(lt);
            ss[i] += e;
        }

        // write next tile into the other buffer
        if (pf) {
            char* db = lds + (c ^ 1) * 32768;
            #pragma unroll
            for (int k = 0; k < 4; k++) {
                *(uint4*)(db + swz(srow, s4 + k))         = ph[k];
                *(uint4*)(db + 16384 + swz(srow, s4 + k)) = pl[k];
            }
        }
        __syncthreads();
    }

    // ---- per-row reduce over 32 col-lanes, write per-wave partial ----
    #pragma unroll
    for (int i = 0; i < 16; i++) {
        float v = ss[i];
        v += __shfl_xor(v, 1);
        v += __shfl_xor(v, 2);
        v += __shfl_xor(v, 4);
        v += __shfl_xor(v, 8);
        v += __shfl_xor(v, 16);
        if (ln31 == 0) {
            int grow = m0 + wr * 32 + (i & 3) + 8 * (i >> 2) + 4 * half;
            ps[(size_t)grow * 2 + wc] = v;
        }
    }
}

// ---------------------------------------------------------------------------
// combine: loss = log(exp(t-60) + S) + 60 - t
// ---------------------------------------------------------------------------
__global__ __launch_bounds__(256) void combine_kernel(
    const float* __restrict__ tl, const float* __restrict__ ps,
    float* __restrict__ out)
{
    int r = blockIdx.x * 256 + threadIdx.x;
    if (r >= BB) return;
    float t = tl[r];
    float S = ps[(size_t)r * 2] + ps[(size_t)r * 2 + 1];
    out[r] = logf(expf(t - 60.0f) + S) + 60.0f - t;
}

// ---------------------------------------------------------------------------
extern "C" void kernel_launch(void* const* d_in, const int* in_sizes, int n_in,
                              void* d_out, int out_size, void* d_ws, size_t ws_size,
                              hipStream_t stream)
{
    const float* x    = (const float*)d_in[0];
    const int*   tgt  = (const int*)d_in[1];
    const float* emb  = (const float*)d_in[2];
    const float* bias = (const float*)d_in[3];
    float* out = (float*)d_out;

    char* w = (char*)d_ws;
    int*            ids  = (int*)(w + 0);                    //  32 KB
    float*          corr = (float*)(w + 32768);              //  32 KB
    float*          tl   = (float*)(w + 65536);              //  64 KB
    unsigned*       flag = (unsigned*)(w + 131072);          //   4 B
    unsigned short* Wh   = (unsigned short*)(w + 262144);    //   2 MB
    unsigned short* Wl   = (unsigned short*)(w + 262144 + 2097152);
    float*          ps   = (float*)(w + 262144 + 4194304);   // 128 KB

    const float logr  = (float)log(1000001.0);
    const float logns = (float)log(8192.0);

    detect_kernel<<<dim3(1), dim3(256), 0, stream>>>((const unsigned*)tgt, flag);
    sample_kernel<<<dim3(NSAMP / 256), dim3(256), 0, stream>>>(
        bias, ids, corr, logr, logns);
    wprep_kernel<<<dim3(NSAMP * DD / 256), dim3(256), 0, stream>>>(
        emb, ids, Wh, Wl);
    true_kernel<<<dim3(BB / 256), dim3(256), 0, stream>>>(
        x, tgt, emb, bias, flag, tl, logr, logns);
    gemm_kernel<<<dim3(BB / 64), dim3(256), 0, stream>>>(
        x, tgt, flag, Wh, Wl, ids, corr, ps);
    combine_kernel<<<dim3(BB / 256), dim3(256), 0, stream>>>(tl, ps, out);
}

// Round 13
// 130.898 us; speedup vs baseline: 11.1912x; 2.1482x over previous
//
#include <hip/hip_runtime.h>
#include <math.h>

#define BB      16384   // batch rows
#define DD      128     // embedding dim
#define VV      1000000 // vocab
#define NSAMP   8192    // NUM_SAMPLED
#define NT      (NSAMP / 64)   // 128 N-tiles of 64 candidates

typedef __attribute__((ext_vector_type(8)))  unsigned short u16x8;
typedef __attribute__((ext_vector_type(8)))  __bf16         bf16x8;
typedef __attribute__((ext_vector_type(16))) float          f32x16;

__device__ __forceinline__ unsigned rotl32(unsigned x, unsigned r) {
    return (x << r) | (x >> (32u - r));
}

// RNE float -> bf16
__device__ __forceinline__ unsigned short bf16r(float v) {
    unsigned b = __builtin_bit_cast(unsigned, v);
    unsigned r = (b + 0x7fffu + ((b >> 16) & 1u)) >> 16;
    return (unsigned short)r;
}

// ---------------------------------------------------------------------------
// XLA:CPU vectorized f32 exp (Cephes, NO FMA — VERIFIED R10/R12).
// ---------------------------------------------------------------------------
__device__ __forceinline__ float xla_expf(float x) {
#pragma clang fp contract(off)
    float fx = floorf(x * 1.44269504088896341f + 0.5f);
    float tmp = fx * 0.693359375f;
    float z2  = fx * -2.12194440e-4f;
    float r = x - tmp;
    r = r - z2;
    float z = r * r;
    float y = 1.9875691500E-4f;
    y = y * r + 1.3981999507E-3f;
    y = y * r + 8.3334519073E-3f;
    y = y * r + 4.1665795894E-2f;
    y = y * r + 1.6666665459E-1f;
    y = y * r + 5.0000001201E-1f;
    y = y * z + r;
    y = y + 1.0f;
    int n = (int)fx;
    float p2n = __builtin_bit_cast(float, (unsigned)((n + 127) << 23));
    return y * p2n;
}

__device__ __forceinline__ float log_q32(float idf, float logr) {
    float l2 = (float)log((double)(idf + 2.0f));
    float l1 = (float)log((double)(idf + 1.0f));
    float q  = (l2 - l1) / logr;
    return (float)log((double)q);
}

// ---------------------------------------------------------------------------
// detect target dtype (int32 vs int64). 2048 odd words is plenty of evidence.
// ---------------------------------------------------------------------------
__global__ void detect_kernel(const unsigned* __restrict__ t,
                              unsigned* __restrict__ flag)
{
    __shared__ unsigned red[256];
    unsigned acc = 0;
    for (int i = threadIdx.x; i < 2048; i += 256) acc |= t[2 * i + 1];
    red[threadIdx.x] = acc;
    __syncthreads();
    for (int s = 128; s > 0; s >>= 1) {
        if ((int)threadIdx.x < s) red[threadIdx.x] |= red[threadIdx.x + s];
        __syncthreads();
    }
    if (threadIdx.x == 0) flag[0] = (red[0] == 0u) ? 1u : 0u;
}

// ---------------------------------------------------------------------------
// sample: partitionable threefry + XLA Cephes exp (VERIFIED — unchanged)
// ---------------------------------------------------------------------------
__global__ void sample_kernel(const float* __restrict__ bias,
                              int* __restrict__ ids,
                              float* __restrict__ corr,
                              float logr, float logns)
{
    int i = blockIdx.x * blockDim.x + threadIdx.x;
    if (i >= NSAMP) return;

    const unsigned k0 = 0u, k1 = 1u;
    const unsigned k2 = 0x1BD11BDAu ^ k0 ^ k1;
    unsigned x0 = 0u + k0;
    unsigned x1 = (unsigned)i + k1;
#define TFR(r) { x0 += x1; x1 = rotl32(x1, (r)); x1 ^= x0; }
    TFR(13) TFR(15) TFR(26) TFR(6)   x0 += k1; x1 += k2 + 1u;
    TFR(17) TFR(29) TFR(16) TFR(24)  x0 += k2; x1 += k0 + 2u;
    TFR(13) TFR(15) TFR(26) TFR(6)   x0 += k0; x1 += k1 + 3u;
    TFR(17) TFR(29) TFR(16) TFR(24)  x0 += k1; x1 += k2 + 4u;
    TFR(13) TFR(15) TFR(26) TFR(6)   x0 += k2; x1 += k0 + 5u;
#undef TFR
    unsigned bits = x0 ^ x1;

    unsigned fb = (bits >> 9) | 0x3f800000u;
    float u = __builtin_bit_cast(float, fb) - 1.0f;
    float t = u * logr;
    float ef = xla_expf(t);
    int id = (int)floorf(ef) - 1;
    id = id < 0 ? 0 : (id > VV - 1 ? VV - 1 : id);

    float lp = log_q32((float)id, logr);
    ids[i]  = id;
    corr[i] = bias[id] - (logns + lp);
}

// ---------------------------------------------------------------------------
// wprep: gather sampled rows -> bf16 (RNE). Pure-bf16 GEMM this round:
// rounding-noise budget ~0.1 max over 134M logits vs 0.78 slack. No Wl.
// ---------------------------------------------------------------------------
__global__ __launch_bounds__(256) void wprep_kernel(
    const float* __restrict__ emb, const int* __restrict__ ids,
    unsigned short* __restrict__ Wh)
{
    int g = blockIdx.x * 256 + threadIdx.x;        // 0 .. 8192*128-1
    int row = g >> 7;
    int k   = g & 127;
    Wh[g] = bf16r(emb[(size_t)ids[row] * DD + k]);
}

// ---------------------------------------------------------------------------
// true logit (VERIFIED — unchanged)
// ---------------------------------------------------------------------------
__global__ __launch_bounds__(256) void true_kernel(
    const float* __restrict__ x, const int* __restrict__ tgt,
    const float* __restrict__ emb, const float* __restrict__ bias,
    const unsigned* __restrict__ flag,
    float* __restrict__ tl, float logr, float logns)
{
    int r = blockIdx.x * 256 + threadIdx.x;
    if (r >= BB) return;
    int t = flag[0] ? tgt[2 * r] : tgt[r];
    const float4* xr = (const float4*)(x + (size_t)r * DD);
    const float4* wr = (const float4*)(emb + (size_t)t * DD);
    float a0 = 0.f, a1 = 0.f, a2 = 0.f, a3 = 0.f;
    #pragma unroll
    for (int k = 0; k < 32; k += 4) {
        float4 xv0 = xr[k],   wv0 = wr[k];
        float4 xv1 = xr[k+1], wv1 = wr[k+1];
        float4 xv2 = xr[k+2], wv2 = wr[k+2];
        float4 xv3 = xr[k+3], wv3 = wr[k+3];
        a0 += xv0.x*wv0.x + xv0.y*wv0.y + xv0.z*wv0.z + xv0.w*wv0.w;
        a1 += xv1.x*wv1.x + xv1.y*wv1.y + xv1.z*wv1.z + xv1.w*wv1.w;
        a2 += xv2.x*wv2.x + xv2.y*wv2.y + xv2.z*wv2.z + xv2.w*wv2.w;
        a3 += xv3.x*wv3.x + xv3.y*wv3.y + xv3.z*wv3.z + xv3.w*wv3.w;
    }
    float dot = (a0 + a1) + (a2 + a3);
    float lp  = log_q32((float)t, logr);
    tl[r] = dot + bias[t] - (logns + lp);
}

// ---------------------------------------------------------------------------
// Main GEMM, round 13: pure bf16, 1 MFMA chain, 64x64 tile, 4 waves,
// Wh-only LDS double-buffer (2 x 16 KB = 32 KB) -> 2 blocks/CU.
// grid = (BB/64, 2): blockIdx.y takes half the 128 candidate tiles.
// ps[row][4] partials (y*2 + wc). Fixed-offset LSE exp(l-60), exact in-loop
// hit masking. B row includes wave-column split (R12 fix retained).
// ---------------------------------------------------------------------------
__device__ __forceinline__ int swz(int row, int slot) {
    return row * 256 + ((slot ^ (row & 15)) << 4);
}

__global__ __launch_bounds__(256, 2) void gemm_kernel(
    const float* __restrict__ x, const int* __restrict__ tgt,
    const unsigned* __restrict__ flag,
    const unsigned short* __restrict__ Wh,
    const int* __restrict__ ids, const float* __restrict__ corr,
    float* __restrict__ ps)
{
    __shared__ char lds[32768];   // 2 bufs x 16 KB

    const int tid  = threadIdx.x;
    const int lane = tid & 63;
    const int wid  = tid >> 6;
    const int wr   = wid >> 1, wc = wid & 1;
    const int half = lane >> 5, ln31 = lane & 31;
    const int m0   = blockIdx.x * 64;
    const int ty0  = blockIdx.y * (NT / 2);    // 64 tiles per y-half

    // ---- A fragments: 32 rows x 128 k, bf16, resident in VGPRs ----
    u16x8 ah[8];
    {
        const float* xr = x + (size_t)(m0 + wr * 32 + ln31) * DD;
        #pragma unroll
        for (int ks = 0; ks < 8; ks++) {
            const float4* p = (const float4*)(xr + ks * 16 + half * 8);
            float4 f0 = p[0], f1 = p[1];
            float v[8] = {f0.x, f0.y, f0.z, f0.w, f1.x, f1.y, f1.z, f1.w};
            u16x8 h;
            #pragma unroll
            for (int j = 0; j < 8; j++) h[j] = bf16r(v[j]);
            ah[ks] = h;
        }
    }

    // ---- targets for this lane's 16 C rows ----
    const unsigned is64 = flag[0];
    int t16[16];
    #pragma unroll
    for (int i = 0; i < 16; i++) {
        int grow = m0 + wr * 32 + (i & 3) + 8 * (i >> 2) + 4 * half;
        t16[i] = is64 ? tgt[2 * grow] : tgt[grow];
    }

    float ss[16];
    #pragma unroll
    for (int i = 0; i < 16; i++) ss[i] = 0.f;

    const int srow = tid >> 2, s4 = (tid & 3) * 4;
    const int brow = wc * 32 + ln31;

    // ---- prologue: stage first tile into buf 0 ----
    {
        const uint4* wh = (const uint4*)(Wh + (size_t)(ty0 * 64 + srow) * DD);
        #pragma unroll
        for (int k = 0; k < 4; k++)
            *(uint4*)(lds + swz(srow, s4 + k)) = wh[s4 + k];
    }
    __syncthreads();

    for (int t = 0; t < NT / 2; t++) {
        const int c = t & 1;
        // issue next-tile global loads early (hide under MFMA)
        uint4 ph[4];
        const bool pf = (t + 1 < NT / 2);
        if (pf) {
            const uint4* wh = (const uint4*)(Wh + (size_t)((ty0 + t + 1) * 64 + srow) * DD);
            #pragma unroll
            for (int k = 0; k < 4; k++) ph[k] = wh[s4 + k];
        }

        // compute current tile
        const char* bh_base = lds + c * 16384;
        f32x16 hh;
        #pragma unroll
        for (int q = 0; q < 16; q++) hh[q] = 0.f;

        #pragma unroll
        for (int ks = 0; ks < 8; ks++) {
            int off = swz(brow, ks * 2 + half);
            bf16x8 bh = __builtin_bit_cast(bf16x8, *(const uint4*)(bh_base + off));
            bf16x8 a_h = __builtin_bit_cast(bf16x8, ah[ks]);
            hh = __builtin_amdgcn_mfma_f32_32x32x16_bf16(a_h, bh, hh, 0, 0, 0);
        }

        // epilogue: logit = C + corr - 60; exact hit mask; accumulate exp
        const int j = (ty0 + t) * 64 + wc * 32 + ln31;
        const float cc = corr[j] - 60.0f;
        const int idj = ids[j];
        #pragma unroll
        for (int i = 0; i < 16; i++) {
            float lt = hh[i] + cc;
            float e = (idj == t16[i]) ? 0.0f : __expf(lt);
            ss[i] += e;
        }

        // write next tile into the other buffer
        if (pf) {
            char* db = lds + (c ^ 1) * 16384;
            #pragma unroll
            for (int k = 0; k < 4; k++)
                *(uint4*)(db + swz(srow, s4 + k)) = ph[k];
        }
        __syncthreads();
    }

    // ---- per-row reduce over 32 col-lanes, write per-wave partial ----
    #pragma unroll
    for (int i = 0; i < 16; i++) {
        float v = ss[i];
        v += __shfl_xor(v, 1);
        v += __shfl_xor(v, 2);
        v += __shfl_xor(v, 4);
        v += __shfl_xor(v, 8);
        v += __shfl_xor(v, 16);
        if (ln31 == 0) {
            int grow = m0 + wr * 32 + (i & 3) + 8 * (i >> 2) + 4 * half;
            ps[(size_t)grow * 4 + blockIdx.y * 2 + wc] = v;
        }
    }
}

// ---------------------------------------------------------------------------
// combine: loss = log(exp(t-60) + S) + 60 - t
// ---------------------------------------------------------------------------
__global__ __launch_bounds__(256) void combine_kernel(
    const float* __restrict__ tl, const float* __restrict__ ps,
    float* __restrict__ out)
{
    int r = blockIdx.x * 256 + threadIdx.x;
    if (r >= BB) return;
    float t = tl[r];
    const float* p = ps + (size_t)r * 4;
    float S = (p[0] + p[1]) + (p[2] + p[3]);
    out[r] = logf(expf(t - 60.0f) + S) + 60.0f - t;
}

// ---------------------------------------------------------------------------
extern "C" void kernel_launch(void* const* d_in, const int* in_sizes, int n_in,
                              void* d_out, int out_size, void* d_ws, size_t ws_size,
                              hipStream_t stream)
{
    const float* x    = (const float*)d_in[0];
    const int*   tgt  = (const int*)d_in[1];
    const float* emb  = (const float*)d_in[2];
    const float* bias = (const float*)d_in[3];
    float* out = (float*)d_out;

    char* w = (char*)d_ws;
    int*            ids  = (int*)(w + 0);                    //  32 KB
    float*          corr = (float*)(w + 32768);              //  32 KB
    float*          tl   = (float*)(w + 65536);              //  64 KB
    unsigned*       flag = (unsigned*)(w + 131072);          //   4 B
    unsigned short* Wh   = (unsigned short*)(w + 262144);    //   2 MB
    float*          ps   = (float*)(w + 262144 + 2097152);   // 256 KB

    const float logr  = (float)log(1000001.0);
    const float logns = (float)log(8192.0);

    detect_kernel<<<dim3(1), dim3(256), 0, stream>>>((const unsigned*)tgt, flag);
    sample_kernel<<<dim3(NSAMP / 256), dim3(256), 0, stream>>>(
        bias, ids, corr, logr, logns);
    wprep_kernel<<<dim3(NSAMP * DD / 256), dim3(256), 0, stream>>>(
        emb, ids, Wh);
    true_kernel<<<dim3(BB / 256), dim3(256), 0, stream>>>(
        x, tgt, emb, bias, flag, tl, logr, logns);
    gemm_kernel<<<dim3(BB / 64, 2), dim3(256), 0, stream>>>(
        x, tgt, flag, Wh, ids, corr, ps);
    combine_kernel<<<dim3(BB / 256), dim3(256), 0, stream>>>(tl, ps, out);
}

// Round 14
// 129.225 us; speedup vs baseline: 11.3360x; 1.0129x over previous
//
#include <hip/hip_runtime.h>
#include <math.h>

#define BB      16384   // batch rows
#define DD      128     // embedding dim
#define VV      1000000 // vocab
#define NSAMP   8192    // NUM_SAMPLED
#define NT      (NSAMP / 64)   // 128 N-tiles of 64 candidates

typedef __attribute__((ext_vector_type(8)))  unsigned short u16x8;
typedef __attribute__((ext_vector_type(8)))  __bf16         bf16x8;
typedef __attribute__((ext_vector_type(16))) float          f32x16;

__device__ __forceinline__ unsigned rotl32(unsigned x, unsigned r) {
    return (x << r) | (x >> (32u - r));
}

// RNE float -> bf16
__device__ __forceinline__ unsigned short bf16r(float v) {
    unsigned b = __builtin_bit_cast(unsigned, v);
    unsigned r = (b + 0x7fffu + ((b >> 16) & 1u)) >> 16;
    return (unsigned short)r;
}

// ---------------------------------------------------------------------------
// XLA:CPU vectorized f32 exp (Cephes, NO FMA — VERIFIED R10/R12/R13).
// ---------------------------------------------------------------------------
__device__ __forceinline__ float xla_expf(float x) {
#pragma clang fp contract(off)
    float fx = floorf(x * 1.44269504088896341f + 0.5f);
    float tmp = fx * 0.693359375f;
    float z2  = fx * -2.12194440e-4f;
    float r = x - tmp;
    r = r - z2;
    float z = r * r;
    float y = 1.9875691500E-4f;
    y = y * r + 1.3981999507E-3f;
    y = y * r + 8.3334519073E-3f;
    y = y * r + 4.1665795894E-2f;
    y = y * r + 1.6666665459E-1f;
    y = y * r + 5.0000001201E-1f;
    y = y * z + r;
    y = y + 1.0f;
    int n = (int)fx;
    float p2n = __builtin_bit_cast(float, (unsigned)((n + 127) << 23));
    return y * p2n;
}

__device__ __forceinline__ float log_q32(float idf, float logr) {
    float l2 = (float)log((double)(idf + 2.0f));
    float l1 = (float)log((double)(idf + 1.0f));
    float q  = (l2 - l1) / logr;
    return (float)log((double)q);
}

// ---------------------------------------------------------------------------
// Kernel 1: prep = detect (block 0) + threefry sample + corr + W row gather
// to bf16. Thread i owns candidate i. (VERIFIED numerics, reorganized only.)
// ---------------------------------------------------------------------------
__global__ __launch_bounds__(256) void prep_kernel(
    const unsigned* __restrict__ tgt_raw,
    const float* __restrict__ emb, const float* __restrict__ bias,
    int* __restrict__ ids, float* __restrict__ corr,
    unsigned short* __restrict__ Wh, unsigned* __restrict__ flag,
    float logr, float logns)
{
    // ---- detect target dtype in block 0 (writes flag; consumed by finish) --
    if (blockIdx.x == 0) {
        __shared__ unsigned red[256];
        unsigned acc = 0;
        for (int i = threadIdx.x; i < 2048; i += 256) acc |= tgt_raw[2 * i + 1];
        red[threadIdx.x] = acc;
        __syncthreads();
        for (int s = 128; s > 0; s >>= 1) {
            if ((int)threadIdx.x < s) red[threadIdx.x] |= red[threadIdx.x + s];
            __syncthreads();
        }
        if (threadIdx.x == 0) flag[0] = (red[0] == 0u) ? 1u : 0u;
    }

    int i = blockIdx.x * 256 + threadIdx.x;
    if (i >= NSAMP) return;

    // ---- partitionable threefry2x32(key=(0,1), counter=(0,i)) ----
    const unsigned k0 = 0u, k1 = 1u;
    const unsigned k2 = 0x1BD11BDAu ^ k0 ^ k1;
    unsigned x0 = 0u + k0;
    unsigned x1 = (unsigned)i + k1;
#define TFR(r) { x0 += x1; x1 = rotl32(x1, (r)); x1 ^= x0; }
    TFR(13) TFR(15) TFR(26) TFR(6)   x0 += k1; x1 += k2 + 1u;
    TFR(17) TFR(29) TFR(16) TFR(24)  x0 += k2; x1 += k0 + 2u;
    TFR(13) TFR(15) TFR(26) TFR(6)   x0 += k0; x1 += k1 + 3u;
    TFR(17) TFR(29) TFR(16) TFR(24)  x0 += k1; x1 += k2 + 4u;
    TFR(13) TFR(15) TFR(26) TFR(6)   x0 += k2; x1 += k0 + 5u;
#undef TFR
    unsigned bits = x0 ^ x1;

    unsigned fb = (bits >> 9) | 0x3f800000u;
    float u = __builtin_bit_cast(float, fb) - 1.0f;
    float t = u * logr;
    float ef = xla_expf(t);
    int id = (int)floorf(ef) - 1;
    id = id < 0 ? 0 : (id > VV - 1 ? VV - 1 : id);

    float lp = log_q32((float)id, logr);
    ids[i]  = id;
    corr[i] = bias[id] - (logns + lp);

    // ---- gather candidate row -> bf16 Wh[i][0..127] ----
    const float4* src = (const float4*)(emb + (size_t)id * DD);
    uint4* dst = (uint4*)(Wh + (size_t)i * DD);
    #pragma unroll
    for (int k = 0; k < 16; k++) {
        float4 a = src[2 * k], b = src[2 * k + 1];
        uint4 o;
        o.x = (unsigned)bf16r(a.x) | ((unsigned)bf16r(a.y) << 16);
        o.y = (unsigned)bf16r(a.z) | ((unsigned)bf16r(a.w) << 16);
        o.z = (unsigned)bf16r(b.x) | ((unsigned)bf16r(b.y) << 16);
        o.w = (unsigned)bf16r(b.z) | ((unsigned)bf16r(b.w) << 16);
        dst[k] = o;
    }
}

// ---------------------------------------------------------------------------
// Kernel 2: GEMM (VERIFIED R13 structure: pure bf16, 64x64 tile, 4 waves,
// Wh double-buffer 32 KB, 2 blocks/CU, y-split over candidate halves,
// fixed-offset LSE exp(l-60), exact in-loop hit masking).
// ---------------------------------------------------------------------------
__device__ __forceinline__ int swz(int row, int slot) {
    return row * 256 + ((slot ^ (row & 15)) << 4);
}

__global__ __launch_bounds__(256, 2) void gemm_kernel(
    const float* __restrict__ x, const int* __restrict__ tgt,
    const unsigned* __restrict__ flag,
    const unsigned short* __restrict__ Wh,
    const int* __restrict__ ids, const float* __restrict__ corr,
    float* __restrict__ ps)
{
    __shared__ char lds[32768];   // 2 bufs x 16 KB

    const int tid  = threadIdx.x;
    const int lane = tid & 63;
    const int wid  = tid >> 6;
    const int wr   = wid >> 1, wc = wid & 1;
    const int half = lane >> 5, ln31 = lane & 31;
    const int m0   = blockIdx.x * 64;
    const int ty0  = blockIdx.y * (NT / 2);    // 64 tiles per y-half

    // ---- A fragments: 32 rows x 128 k, bf16, resident in VGPRs ----
    u16x8 ah[8];
    {
        const float* xr = x + (size_t)(m0 + wr * 32 + ln31) * DD;
        #pragma unroll
        for (int ks = 0; ks < 8; ks++) {
            const float4* p = (const float4*)(xr + ks * 16 + half * 8);
            float4 f0 = p[0], f1 = p[1];
            float v[8] = {f0.x, f0.y, f0.z, f0.w, f1.x, f1.y, f1.z, f1.w};
            u16x8 h;
            #pragma unroll
            for (int j = 0; j < 8; j++) h[j] = bf16r(v[j]);
            ah[ks] = h;
        }
    }

    // ---- targets for this lane's 16 C rows ----
    const unsigned is64 = flag[0];
    int t16[16];
    #pragma unroll
    for (int i = 0; i < 16; i++) {
        int grow = m0 + wr * 32 + (i & 3) + 8 * (i >> 2) + 4 * half;
        t16[i] = is64 ? tgt[2 * grow] : tgt[grow];
    }

    float ss[16];
    #pragma unroll
    for (int i = 0; i < 16; i++) ss[i] = 0.f;

    const int srow = tid >> 2, s4 = (tid & 3) * 4;
    const int brow = wc * 32 + ln31;

    // ---- prologue: stage first tile into buf 0 ----
    {
        const uint4* wh = (const uint4*)(Wh + (size_t)(ty0 * 64 + srow) * DD);
        #pragma unroll
        for (int k = 0; k < 4; k++)
            *(uint4*)(lds + swz(srow, s4 + k)) = wh[s4 + k];
    }
    __syncthreads();

    for (int t = 0; t < NT / 2; t++) {
        const int c = t & 1;
        uint4 ph[4];
        const bool pf = (t + 1 < NT / 2);
        if (pf) {
            const uint4* wh = (const uint4*)(Wh + (size_t)((ty0 + t + 1) * 64 + srow) * DD);
            #pragma unroll
            for (int k = 0; k < 4; k++) ph[k] = wh[s4 + k];
        }

        const char* bh_base = lds + c * 16384;
        f32x16 hh;
        #pragma unroll
        for (int q = 0; q < 16; q++) hh[q] = 0.f;

        #pragma unroll
        for (int ks = 0; ks < 8; ks++) {
            int off = swz(brow, ks * 2 + half);
            bf16x8 bh = __builtin_bit_cast(bf16x8, *(const uint4*)(bh_base + off));
            bf16x8 a_h = __builtin_bit_cast(bf16x8, ah[ks]);
            hh = __builtin_amdgcn_mfma_f32_32x32x16_bf16(a_h, bh, hh, 0, 0, 0);
        }

        const int j = (ty0 + t) * 64 + wc * 32 + ln31;
        const float cc = corr[j] - 60.0f;
        const int idj = ids[j];
        #pragma unroll
        for (int i = 0; i < 16; i++) {
            float lt = hh[i] + cc;
            float e = (idj == t16[i]) ? 0.0f : __expf(lt);
            ss[i] += e;
        }

        if (pf) {
            char* db = lds + (c ^ 1) * 16384;
            #pragma unroll
            for (int k = 0; k < 4; k++)
                *(uint4*)(db + swz(srow, s4 + k)) = ph[k];
        }
        __syncthreads();
    }

    #pragma unroll
    for (int i = 0; i < 16; i++) {
        float v = ss[i];
        v += __shfl_xor(v, 1);
        v += __shfl_xor(v, 2);
        v += __shfl_xor(v, 4);
        v += __shfl_xor(v, 8);
        v += __shfl_xor(v, 16);
        if (ln31 == 0) {
            int grow = m0 + wr * 32 + (i & 3) + 8 * (i >> 2) + 4 * half;
            ps[(size_t)grow * 4 + blockIdx.y * 2 + wc] = v;
        }
    }
}

// ---------------------------------------------------------------------------
// Kernel 3: finish = true logit (16 lanes per row, coalesced) + LSE combine.
// loss = log(exp(t-60) + S) + 60 - t, S = sum of 4 gemm partials.
// ---------------------------------------------------------------------------
__global__ __launch_bounds__(256) void finish_kernel(
    const float* __restrict__ x, const int* __restrict__ tgt,
    const float* __restrict__ emb, const float* __restrict__ bias,
    const unsigned* __restrict__ flag, const float* __restrict__ ps,
    float* __restrict__ out, float logr, float logns)
{
    const int gid = blockIdx.x * 256 + threadIdx.x;
    const int r   = gid >> 4;            // row
    const int l   = gid & 15;            // lane-in-row
    if (r >= BB) return;

    const int t = flag[0] ? tgt[2 * r] : tgt[r];

    // cooperative dot: lane l covers float4 slots {l, l+16}
    const float4* xr = (const float4*)(x + (size_t)r * DD);
    const float4* wr = (const float4*)(emb + (size_t)t * DD);
    float4 xa = xr[l], xb = xr[l + 16];
    float4 wa = wr[l], wb = wr[l + 16];
    float d = xa.x*wa.x + xa.y*wa.y + xa.z*wa.z + xa.w*wa.w
            + xb.x*wb.x + xb.y*wb.y + xb.z*wb.z + xb.w*wb.w;
    d += __shfl_xor(d, 1);
    d += __shfl_xor(d, 2);
    d += __shfl_xor(d, 4);
    d += __shfl_xor(d, 8);

    if (l == 0) {
        float lp = log_q32((float)t, logr);
        float tl = d + bias[t] - (logns + lp);
        const float* p = ps + (size_t)r * 4;
        float S = (p[0] + p[1]) + (p[2] + p[3]);
        out[r] = logf(expf(tl - 60.0f) + S) + 60.0f - tl;
    }
}

// ---------------------------------------------------------------------------
extern "C" void kernel_launch(void* const* d_in, const int* in_sizes, int n_in,
                              void* d_out, int out_size, void* d_ws, size_t ws_size,
                              hipStream_t stream)
{
    const float* x    = (const float*)d_in[0];
    const int*   tgt  = (const int*)d_in[1];
    const float* emb  = (const float*)d_in[2];
    const float* bias = (const float*)d_in[3];
    float* out = (float*)d_out;

    char* w = (char*)d_ws;
    int*            ids  = (int*)(w + 0);                    //  32 KB
    float*          corr = (float*)(w + 32768);              //  32 KB
    unsigned*       flag = (unsigned*)(w + 65536);           //   4 B
    unsigned short* Wh   = (unsigned short*)(w + 131072);    //   2 MB
    float*          ps   = (float*)(w + 131072 + 2097152);   // 256 KB

    const float logr  = (float)log(1000001.0);
    const float logns = (float)log(8192.0);

    prep_kernel<<<dim3(NSAMP / 256), dim3(256), 0, stream>>>(
        (const unsigned*)tgt, emb, bias, ids, corr, Wh, flag, logr, logns);
    gemm_kernel<<<dim3(BB / 64, 2), dim3(256), 0, stream>>>(
        x, tgt, flag, Wh, ids, corr, ps);
    finish_kernel<<<dim3(BB * 16 / 256), dim3(256), 0, stream>>>(
        x, tgt, emb, bias, flag, ps, out, logr, logns);
}

// Round 15
// 80.086 us; speedup vs baseline: 18.2917x; 1.6136x over previous
//
#include <hip/hip_runtime.h>
#include <math.h>

#define BB      16384   // batch rows
#define DD      128     // embedding dim
#define VV      1000000 // vocab
#define NSAMP   8192    // NUM_SAMPLED
#define NT      (NSAMP / 64)   // 128 N-tiles of 64 candidates

typedef __attribute__((ext_vector_type(8)))  unsigned short u16x8;
typedef __attribute__((ext_vector_type(8)))  __bf16         bf16x8;
typedef __attribute__((ext_vector_type(16))) float          f32x16;

__device__ __forceinline__ unsigned rotl32(unsigned x, unsigned r) {
    return (x << r) | (x >> (32u - r));
}

// RNE float -> bf16
__device__ __forceinline__ unsigned short bf16r(float v) {
    unsigned b = __builtin_bit_cast(unsigned, v);
    unsigned r = (b + 0x7fffu + ((b >> 16) & 1u)) >> 16;
    return (unsigned short)r;
}

// ---------------------------------------------------------------------------
// XLA:CPU vectorized f32 exp (Cephes, NO FMA — VERIFIED R10/R12/R13/R14).
// ---------------------------------------------------------------------------
__device__ __forceinline__ float xla_expf(float x) {
#pragma clang fp contract(off)
    float fx = floorf(x * 1.44269504088896341f + 0.5f);
    float tmp = fx * 0.693359375f;
    float z2  = fx * -2.12194440e-4f;
    float r = x - tmp;
    r = r - z2;
    float z = r * r;
    float y = 1.9875691500E-4f;
    y = y * r + 1.3981999507E-3f;
    y = y * r + 8.3334519073E-3f;
    y = y * r + 4.1665795894E-2f;
    y = y * r + 1.6666665459E-1f;
    y = y * r + 5.0000001201E-1f;
    y = y * z + r;
    y = y + 1.0f;
    int n = (int)fx;
    float p2n = __builtin_bit_cast(float, (unsigned)((n + 127) << 23));
    return y * p2n;
}

__device__ __forceinline__ float log_q32(float idf, float logr) {
    float l2 = (float)log((double)(idf + 2.0f));
    float l1 = (float)log((double)(idf + 1.0f));
    float q  = (l2 - l1) / logr;
    return (float)log((double)q);
}

// ---------------------------------------------------------------------------
// Kernel 1: sample = detect (block 0) + threefry + exp-floor ids + corr.
// (VERIFIED numerics — unchanged.)
// ---------------------------------------------------------------------------
__global__ __launch_bounds__(256) void sample_kernel(
    const unsigned* __restrict__ tgt_raw,
    const float* __restrict__ bias,
    int* __restrict__ ids, float* __restrict__ corr,
    unsigned* __restrict__ flag, float logr, float logns)
{
    if (blockIdx.x == 0) {
        __shared__ unsigned red[256];
        unsigned acc = 0;
        for (int i = threadIdx.x; i < 2048; i += 256) acc |= tgt_raw[2 * i + 1];
        red[threadIdx.x] = acc;
        __syncthreads();
        for (int s = 128; s > 0; s >>= 1) {
            if ((int)threadIdx.x < s) red[threadIdx.x] |= red[threadIdx.x + s];
            __syncthreads();
        }
        if (threadIdx.x == 0) flag[0] = (red[0] == 0u) ? 1u : 0u;
    }

    int i = blockIdx.x * 256 + threadIdx.x;
    if (i >= NSAMP) return;

    const unsigned k0 = 0u, k1 = 1u;
    const unsigned k2 = 0x1BD11BDAu ^ k0 ^ k1;
    unsigned x0 = 0u + k0;
    unsigned x1 = (unsigned)i + k1;
#define TFR(r) { x0 += x1; x1 = rotl32(x1, (r)); x1 ^= x0; }
    TFR(13) TFR(15) TFR(26) TFR(6)   x0 += k1; x1 += k2 + 1u;
    TFR(17) TFR(29) TFR(16) TFR(24)  x0 += k2; x1 += k0 + 2u;
    TFR(13) TFR(15) TFR(26) TFR(6)   x0 += k0; x1 += k1 + 3u;
    TFR(17) TFR(29) TFR(16) TFR(24)  x0 += k1; x1 += k2 + 4u;
    TFR(13) TFR(15) TFR(26) TFR(6)   x0 += k2; x1 += k0 + 5u;
#undef TFR
    unsigned bits = x0 ^ x1;

    unsigned fb = (bits >> 9) | 0x3f800000u;
    float u = __builtin_bit_cast(float, fb) - 1.0f;
    float t = u * logr;
    float ef = xla_expf(t);
    int id = (int)floorf(ef) - 1;
    id = id < 0 ? 0 : (id > VV - 1 ? VV - 1 : id);

    float lp = log_q32((float)id, logr);
    ids[i]  = id;
    corr[i] = bias[id] - (logns + lp);
}

// ---------------------------------------------------------------------------
// Kernel 2: gather candidate rows -> bf16 Wh. Thread per 8 elements:
// 16 threads/row read 512 B contiguous (coalesced), 512 blocks.
// ---------------------------------------------------------------------------
__global__ __launch_bounds__(256) void gather_kernel(
    const float* __restrict__ emb, const int* __restrict__ ids,
    unsigned short* __restrict__ Wh)
{
    int g = blockIdx.x * 256 + threadIdx.x;    // 0 .. 131071
    int row   = g >> 4;
    int chunk = g & 15;
    const float4* src = (const float4*)(emb + (size_t)ids[row] * DD + chunk * 8);
    float4 a = src[0], b = src[1];
    uint4 o;
    o.x = (unsigned)bf16r(a.x) | ((unsigned)bf16r(a.y) << 16);
    o.y = (unsigned)bf16r(a.z) | ((unsigned)bf16r(a.w) << 16);
    o.z = (unsigned)bf16r(b.x) | ((unsigned)bf16r(b.y) << 16);
    o.w = (unsigned)bf16r(b.z) | ((unsigned)bf16r(b.w) << 16);
    *(uint4*)(Wh + (size_t)row * DD + chunk * 8) = o;
}

// ---------------------------------------------------------------------------
// Kernel 3: GEMM. R15 structure: block = 128 rows x 64-candidate tiles,
// 4 waves (2 Mhalf x 2 Ncol). Each wave: 64 rows x 32 candidates via TWO
// A-fragment sets + TWO independent MFMA chains (16 MFMA per tile, 8 b128
// reads per tile -> 2x arithmetic intensity per LDS byte vs R13; MFMA pipe
// becomes the limit). Wh double-buffer 32 KB, 2 blocks/CU, y=4 split.
// Fixed-offset LSE exp(l-60), exact in-loop hit masking (both VERIFIED).
// ---------------------------------------------------------------------------
__device__ __forceinline__ int swz(int row, int slot) {
    return row * 256 + ((slot ^ (row & 15)) << 4);
}

__global__ __launch_bounds__(256, 2) void gemm_kernel(
    const float* __restrict__ x, const int* __restrict__ tgt,
    const unsigned* __restrict__ flag,
    const unsigned short* __restrict__ Wh,
    const int* __restrict__ ids, const float* __restrict__ corr,
    float* __restrict__ ps)
{
    __shared__ char lds[32768];   // 2 bufs x 16 KB

    const int tid  = threadIdx.x;
    const int lane = tid & 63;
    const int wid  = tid >> 6;
    const int wr   = wid >> 1, wc = wid & 1;
    const int half = lane >> 5, ln31 = lane & 31;
    const int m0   = blockIdx.x * 128;
    const int ty0  = blockIdx.y * (NT / 4);    // 32 tiles per y-quarter

    // ---- A fragments: two sets of 32 rows x 128 k, bf16, in VGPRs ----
    u16x8 ah[2][8];
    #pragma unroll
    for (int p = 0; p < 2; p++) {
        const float* xr = x + (size_t)(m0 + wr * 64 + p * 32 + ln31) * DD;
        #pragma unroll
        for (int ks = 0; ks < 8; ks++) {
            const float4* pp = (const float4*)(xr + ks * 16 + half * 8);
            float4 f0 = pp[0], f1 = pp[1];
            float v[8] = {f0.x, f0.y, f0.z, f0.w, f1.x, f1.y, f1.z, f1.w};
            u16x8 h;
            #pragma unroll
            for (int j = 0; j < 8; j++) h[j] = bf16r(v[j]);
            ah[p][ks] = h;
        }
    }

    // ---- targets for this lane's 32 C rows ----
    const unsigned is64 = flag[0];
    int t32[2][16];
    #pragma unroll
    for (int p = 0; p < 2; p++)
        #pragma unroll
        for (int i = 0; i < 16; i++) {
            int grow = m0 + wr * 64 + p * 32 + (i & 3) + 8 * (i >> 2) + 4 * half;
            t32[p][i] = is64 ? tgt[2 * grow] : tgt[grow];
        }

    float ss[2][16];
    #pragma unroll
    for (int p = 0; p < 2; p++)
        #pragma unroll
        for (int i = 0; i < 16; i++) ss[p][i] = 0.f;

    const int srow = tid >> 2, s4 = (tid & 3) * 4;
    const int brow = wc * 32 + ln31;

    // ---- prologue: stage first tile into buf 0 ----
    {
        const uint4* wh = (const uint4*)(Wh + (size_t)(ty0 * 64 + srow) * DD);
        #pragma unroll
        for (int k = 0; k < 4; k++)
            *(uint4*)(lds + swz(srow, s4 + k)) = wh[s4 + k];
    }
    __syncthreads();

    for (int t = 0; t < NT / 4; t++) {
        const int c = t & 1;
        uint4 ph[4];
        const bool pf = (t + 1 < NT / 4);
        if (pf) {
            const uint4* wh = (const uint4*)(Wh + (size_t)((ty0 + t + 1) * 64 + srow) * DD);
            #pragma unroll
            for (int k = 0; k < 4; k++) ph[k] = wh[s4 + k];
        }

        const char* bh_base = lds + c * 16384;
        f32x16 h0, h1;
        #pragma unroll
        for (int q = 0; q < 16; q++) { h0[q] = 0.f; h1[q] = 0.f; }

        #pragma unroll
        for (int ks = 0; ks < 8; ks++) {
            int off = swz(brow, ks * 2 + half);
            bf16x8 bh = __builtin_bit_cast(bf16x8, *(const uint4*)(bh_base + off));
            bf16x8 a0 = __builtin_bit_cast(bf16x8, ah[0][ks]);
            bf16x8 a1 = __builtin_bit_cast(bf16x8, ah[1][ks]);
            h0 = __builtin_amdgcn_mfma_f32_32x32x16_bf16(a0, bh, h0, 0, 0, 0);
            h1 = __builtin_amdgcn_mfma_f32_32x32x16_bf16(a1, bh, h1, 0, 0, 0);
        }

        // epilogue: logit = C + corr - 60; exact hit mask; accumulate exp
        const int j = (ty0 + t) * 64 + wc * 32 + ln31;
        const float cc = corr[j] - 60.0f;
        const int idj = ids[j];
        #pragma unroll
        for (int i = 0; i < 16; i++) {
            float l0 = h0[i] + cc;
            float l1 = h1[i] + cc;
            ss[0][i] += (idj == t32[0][i]) ? 0.0f : __expf(l0);
            ss[1][i] += (idj == t32[1][i]) ? 0.0f : __expf(l1);
        }

        if (pf) {
            char* db = lds + (c ^ 1) * 16384;
            #pragma unroll
            for (int k = 0; k < 4; k++)
                *(uint4*)(db + swz(srow, s4 + k)) = ph[k];
        }
        __syncthreads();
    }

    // ---- per-row reduce over 32 col-lanes, write per-wave partial ----
    #pragma unroll
    for (int p = 0; p < 2; p++)
        #pragma unroll
        for (int i = 0; i < 16; i++) {
            float v = ss[p][i];
            v += __shfl_xor(v, 1);
            v += __shfl_xor(v, 2);
            v += __shfl_xor(v, 4);
            v += __shfl_xor(v, 8);
            v += __shfl_xor(v, 16);
            if (ln31 == 0) {
                int grow = m0 + wr * 64 + p * 32 + (i & 3) + 8 * (i >> 2) + 4 * half;
                ps[(size_t)grow * 8 + blockIdx.y * 2 + wc] = v;
            }
        }
}

// ---------------------------------------------------------------------------
// Kernel 4: finish = true logit (16 lanes/row, coalesced) + LSE combine.
// loss = log(exp(t-60) + S) + 60 - t, S = sum of 8 gemm partials.
// ---------------------------------------------------------------------------
__global__ __launch_bounds__(256) void finish_kernel(
    const float* __restrict__ x, const int* __restrict__ tgt,
    const float* __restrict__ emb, const float* __restrict__ bias,
    const unsigned* __restrict__ flag, const float* __restrict__ ps,
    float* __restrict__ out, float logr, float logns)
{
    const int gid = blockIdx.x * 256 + threadIdx.x;
    const int r   = gid >> 4;            // row
    const int l   = gid & 15;            // lane-in-row
    if (r >= BB) return;

    const int t = flag[0] ? tgt[2 * r] : tgt[r];

    const float4* xr = (const float4*)(x + (size_t)r * DD);
    const float4* wr = (const float4*)(emb + (size_t)t * DD);
    float4 xa = xr[l], xb = xr[l + 16];
    float4 wa = wr[l], wb = wr[l + 16];
    float d = xa.x*wa.x + xa.y*wa.y + xa.z*wa.z + xa.w*wa.w
            + xb.x*wb.x + xb.y*wb.y + xb.z*wb.z + xb.w*wb.w;
    d += __shfl_xor(d, 1);
    d += __shfl_xor(d, 2);
    d += __shfl_xor(d, 4);
    d += __shfl_xor(d, 8);

    if (l == 0) {
        float lp = log_q32((float)t, logr);
        float tl = d + bias[t] - (logns + lp);
        const float* p = ps + (size_t)r * 8;
        float S = ((p[0] + p[1]) + (p[2] + p[3])) + ((p[4] + p[5]) + (p[6] + p[7]));
        out[r] = logf(expf(tl - 60.0f) + S) + 60.0f - tl;
    }
}

// ---------------------------------------------------------------------------
extern "C" void kernel_launch(void* const* d_in, const int* in_sizes, int n_in,
                              void* d_out, int out_size, void* d_ws, size_t ws_size,
                              hipStream_t stream)
{
    const float* x    = (const float*)d_in[0];
    const int*   tgt  = (const int*)d_in[1];
    const float* emb  = (const float*)d_in[2];
    const float* bias = (const float*)d_in[3];
    float* out = (float*)d_out;

    char* w = (char*)d_ws;
    int*            ids  = (int*)(w + 0);                    //  32 KB
    float*          corr = (float*)(w + 32768);              //  32 KB
    unsigned*       flag = (unsigned*)(w + 65536);           //   4 B
    unsigned short* Wh   = (unsigned short*)(w + 131072);    //   2 MB
    float*          ps   = (float*)(w + 131072 + 2097152);   // 512 KB

    const float logr  = (float)log(1000001.0);
    const float logns = (float)log(8192.0);

    sample_kernel<<<dim3(NSAMP / 256), dim3(256), 0, stream>>>(
        (const unsigned*)tgt, bias, ids, corr, flag, logr, logns);
    gather_kernel<<<dim3(NSAMP * 16 / 256), dim3(256), 0, stream>>>(
        emb, ids, Wh);
    gemm_kernel<<<dim3(BB / 128, 4), dim3(256), 0, stream>>>(
        x, tgt, flag, Wh, ids, corr, ps);
    finish_kernel<<<dim3(BB * 16 / 256), dim3(256), 0, stream>>>(
        x, tgt, emb, bias, flag, ps, out, logr, logns);
}

// Round 16
// 75.054 us; speedup vs baseline: 19.5179x; 1.0670x over previous
//
#include <hip/hip_runtime.h>
#include <math.h>

#define BB      16384   // batch rows
#define DD      128     // embedding dim
#define VV      1000000 // vocab
#define NSAMP   8192    // NUM_SAMPLED
#define NT      (NSAMP / 64)   // 128 N-tiles of 64 candidates

typedef __attribute__((ext_vector_type(8)))  unsigned short u16x8;
typedef __attribute__((ext_vector_type(8)))  __bf16         bf16x8;
typedef __attribute__((ext_vector_type(16))) float          f32x16;

__device__ __forceinline__ unsigned rotl32(unsigned x, unsigned r) {
    return (x << r) | (x >> (32u - r));
}

// RNE float -> bf16
__device__ __forceinline__ unsigned short bf16r(float v) {
    unsigned b = __builtin_bit_cast(unsigned, v);
    unsigned r = (b + 0x7fffu + ((b >> 16) & 1u)) >> 16;
    return (unsigned short)r;
}

// async 16B global -> LDS (per-lane global src, wave-uniform LDS base;
// HW writes base + lane*16)
__device__ __forceinline__ void gload16(const void* g, void* l) {
    __builtin_amdgcn_global_load_lds(
        (const __attribute__((address_space(1))) unsigned*)g,
        (__attribute__((address_space(3))) unsigned*)l, 16, 0, 0);
}

// ---------------------------------------------------------------------------
// XLA:CPU vectorized f32 exp (Cephes, NO FMA — VERIFIED R10-R15).
// ---------------------------------------------------------------------------
__device__ __forceinline__ float xla_expf(float x) {
#pragma clang fp contract(off)
    float fx = floorf(x * 1.44269504088896341f + 0.5f);
    float tmp = fx * 0.693359375f;
    float z2  = fx * -2.12194440e-4f;
    float r = x - tmp;
    r = r - z2;
    float z = r * r;
    float y = 1.9875691500E-4f;
    y = y * r + 1.3981999507E-3f;
    y = y * r + 8.3334519073E-3f;
    y = y * r + 4.1665795894E-2f;
    y = y * r + 1.6666665459E-1f;
    y = y * r + 5.0000001201E-1f;
    y = y * z + r;
    y = y + 1.0f;
    int n = (int)fx;
    float p2n = __builtin_bit_cast(float, (unsigned)((n + 127) << 23));
    return y * p2n;
}

__device__ __forceinline__ float log_q32(float idf, float logr) {
    float l2 = (float)log((double)(idf + 2.0f));
    float l1 = (float)log((double)(idf + 1.0f));
    float q  = (l2 - l1) / logr;
    return (float)log((double)q);
}

// ---------------------------------------------------------------------------
// Kernel 1: prep = x->bf16 (all 1024 blocks) + detect (block 0) +
// threefry sample/corr (blocks 0..31). VERIFIED numerics, reorganized only.
// ---------------------------------------------------------------------------
__global__ __launch_bounds__(256) void prep_kernel(
    const float* __restrict__ x, const unsigned* __restrict__ tgt_raw,
    const float* __restrict__ bias,
    unsigned short* __restrict__ Xb,
    int* __restrict__ ids, float* __restrict__ corr,
    unsigned* __restrict__ flag, float logr, float logns)
{
    // ---- detect target dtype (block 0) ----
    if (blockIdx.x == 0) {
        __shared__ unsigned red[256];
        unsigned acc = 0;
        for (int i = threadIdx.x; i < 2048; i += 256) acc |= tgt_raw[2 * i + 1];
        red[threadIdx.x] = acc;
        __syncthreads();
        for (int s = 128; s > 0; s >>= 1) {
            if ((int)threadIdx.x < s) red[threadIdx.x] |= red[threadIdx.x + s];
            __syncthreads();
        }
        if (threadIdx.x == 0) flag[0] = (red[0] == 0u) ? 1u : 0u;
    }

    // ---- x -> bf16 (thread per 8 elements) ----
    int g = blockIdx.x * 256 + threadIdx.x;        // 0 .. 262143
    {
        int row = g >> 4, chunk = g & 15;
        const float4* src = (const float4*)(x + (size_t)row * DD + chunk * 8);
        float4 a = src[0], b = src[1];
        uint4 o;
        o.x = (unsigned)bf16r(a.x) | ((unsigned)bf16r(a.y) << 16);
        o.y = (unsigned)bf16r(a.z) | ((unsigned)bf16r(a.w) << 16);
        o.z = (unsigned)bf16r(b.x) | ((unsigned)bf16r(b.y) << 16);
        o.w = (unsigned)bf16r(b.z) | ((unsigned)bf16r(b.w) << 16);
        *(uint4*)(Xb + (size_t)row * DD + chunk * 8) = o;
    }

    // ---- sampling (first 8192 threads) ----
    if (g < NSAMP) {
        int i = g;
        const unsigned k0 = 0u, k1 = 1u;
        const unsigned k2 = 0x1BD11BDAu ^ k0 ^ k1;
        unsigned x0 = 0u + k0;
        unsigned x1 = (unsigned)i + k1;
#define TFR(r) { x0 += x1; x1 = rotl32(x1, (r)); x1 ^= x0; }
        TFR(13) TFR(15) TFR(26) TFR(6)   x0 += k1; x1 += k2 + 1u;
        TFR(17) TFR(29) TFR(16) TFR(24)  x0 += k2; x1 += k0 + 2u;
        TFR(13) TFR(15) TFR(26) TFR(6)   x0 += k0; x1 += k1 + 3u;
        TFR(17) TFR(29) TFR(16) TFR(24)  x0 += k1; x1 += k2 + 4u;
        TFR(13) TFR(15) TFR(26) TFR(6)   x0 += k2; x1 += k0 + 5u;
#undef TFR
        unsigned bits = x0 ^ x1;

        unsigned fb = (bits >> 9) | 0x3f800000u;
        float u = __builtin_bit_cast(float, fb) - 1.0f;
        float t = u * logr;
        float ef = xla_expf(t);
        int id = (int)floorf(ef) - 1;
        id = id < 0 ? 0 : (id > VV - 1 ? VV - 1 : id);

        float lp = log_q32((float)id, logr);
        ids[i]  = id;
        corr[i] = bias[id] - (logns + lp);
    }
}

// ---------------------------------------------------------------------------
// Kernel 2: gather candidate rows -> bf16 Wh (coalesced, 512 blocks).
// ---------------------------------------------------------------------------
__global__ __launch_bounds__(256) void gather_kernel(
    const float* __restrict__ emb, const int* __restrict__ ids,
    unsigned short* __restrict__ Wh)
{
    int g = blockIdx.x * 256 + threadIdx.x;    // 0 .. 131071
    int row   = g >> 4;
    int chunk = g & 15;
    const float4* src = (const float4*)(emb + (size_t)ids[row] * DD + chunk * 8);
    float4 a = src[0], b = src[1];
    uint4 o;
    o.x = (unsigned)bf16r(a.x) | ((unsigned)bf16r(a.y) << 16);
    o.y = (unsigned)bf16r(a.z) | ((unsigned)bf16r(a.w) << 16);
    o.z = (unsigned)bf16r(b.x) | ((unsigned)bf16r(b.y) << 16);
    o.w = (unsigned)bf16r(b.z) | ((unsigned)bf16r(b.w) << 16);
    *(uint4*)(Wh + (size_t)row * DD + chunk * 8) = o;
}

// ---------------------------------------------------------------------------
// Kernel 3: GEMM (R15 verified structure) + global_load_lds B-staging with
// inverse-swizzled per-lane global src (rule #21: linear LDS dest + swz read)
// + direct bf16 A loads from Xb. 128 rows x 64-cand tiles, 4 waves, 2 chains,
// 32 KB LDS double-buffer, 2 blocks/CU, y=4. Fixed-offset LSE exp(l-60),
// exact in-loop hit masking.
// ---------------------------------------------------------------------------
__device__ __forceinline__ int swz(int row, int slot) {
    return row * 256 + ((slot ^ (row & 15)) << 4);
}

__global__ __launch_bounds__(256, 2) void gemm_kernel(
    const unsigned short* __restrict__ Xb, const int* __restrict__ tgt,
    const unsigned* __restrict__ flag,
    const unsigned short* __restrict__ Wh,
    const int* __restrict__ ids, const float* __restrict__ corr,
    float* __restrict__ ps)
{
    __shared__ char lds[32768];   // 2 bufs x 16 KB

    const int tid  = threadIdx.x;
    const int lane = tid & 63;
    const int wid  = tid >> 6;
    const int wr   = wid >> 1, wc = wid & 1;
    const int half = lane >> 5, ln31 = lane & 31;
    const int m0   = blockIdx.x * 128;
    const int ty0  = blockIdx.y * (NT / 4);    // 32 tiles per y-quarter

    // ---- A fragments: two sets of 32 rows x 128 k, bf16 direct loads ----
    u16x8 ah[2][8];
    #pragma unroll
    for (int p = 0; p < 2; p++) {
        const uint4* xr = (const uint4*)(Xb + (size_t)(m0 + wr * 64 + p * 32 + ln31) * DD);
        #pragma unroll
        for (int ks = 0; ks < 8; ks++)
            ah[p][ks] = __builtin_bit_cast(u16x8, xr[ks * 2 + half]);
    }

    // ---- targets for this lane's 32 C rows ----
    const unsigned is64 = flag[0];
    int t32[2][16];
    #pragma unroll
    for (int p = 0; p < 2; p++)
        #pragma unroll
        for (int i = 0; i < 16; i++) {
            int grow = m0 + wr * 64 + p * 32 + (i & 3) + 8 * (i >> 2) + 4 * half;
            t32[p][i] = is64 ? tgt[2 * grow] : tgt[grow];
        }

    float ss[2][16];
    #pragma unroll
    for (int p = 0; p < 2; p++)
        #pragma unroll
        for (int i = 0; i < 16; i++) ss[p][i] = 0.f;

    // ---- staging geometry: wave wid stages rows wid*16..wid*16+15 ----
    // LDS is LINEAR (row*256 + u*16); global src is INVERSE-swizzled so the
    // swizzled ds_read returns original slots. 4 instrs x (4 rows x 16 slots).
    const int u    = lane & 15;      // physical 16B slot
    const int rsub = lane >> 4;      // row within instr group
    int srcoff[4], ldsrow[4];
    #pragma unroll
    for (int i2 = 0; i2 < 4; i2++) {
        int row = wid * 16 + i2 * 4 + rsub;
        srcoff[i2] = row * 256 + ((u ^ (row & 15)) << 4);
        ldsrow[i2] = (wid * 16 + i2 * 4) * 256;    // wave-uniform base
    }
    const int brow = wc * 32 + ln31;

    // ---- prologue: DMA tile ty0 into buf 0 ----
    {
        const char* tb = (const char*)Wh + (size_t)(ty0 * 64) * 256;
        #pragma unroll
        for (int i2 = 0; i2 < 4; i2++)
            gload16(tb + srcoff[i2], lds + ldsrow[i2]);
    }
    __syncthreads();

    for (int t = 0; t < NT / 4; t++) {
        const int c = t & 1;
        // DMA next tile into the other buffer (overlaps with MFMA below;
        // the closing __syncthreads drains vmcnt)
        if (t + 1 < NT / 4) {
            const char* tb = (const char*)Wh + (size_t)((ty0 + t + 1) * 64) * 256;
            char* db = lds + (c ^ 1) * 16384;
            #pragma unroll
            for (int i2 = 0; i2 < 4; i2++)
                gload16(tb + srcoff[i2], db + ldsrow[i2]);
        }

        const char* bh_base = lds + c * 16384;
        f32x16 h0, h1;
        #pragma unroll
        for (int q = 0; q < 16; q++) { h0[q] = 0.f; h1[q] = 0.f; }

        #pragma unroll
        for (int ks = 0; ks < 8; ks++) {
            int off = swz(brow, ks * 2 + half);
            bf16x8 bh = __builtin_bit_cast(bf16x8, *(const uint4*)(bh_base + off));
            bf16x8 a0 = __builtin_bit_cast(bf16x8, ah[0][ks]);
            bf16x8 a1 = __builtin_bit_cast(bf16x8, ah[1][ks]);
            h0 = __builtin_amdgcn_mfma_f32_32x32x16_bf16(a0, bh, h0, 0, 0, 0);
            h1 = __builtin_amdgcn_mfma_f32_32x32x16_bf16(a1, bh, h1, 0, 0, 0);
        }

        // epilogue: logit = C + corr - 60; exact hit mask; accumulate exp
        const int j = (ty0 + t) * 64 + wc * 32 + ln31;
        const float cc = corr[j] - 60.0f;
        const int idj = ids[j];
        #pragma unroll
        for (int i = 0; i < 16; i++) {
            float l0 = h0[i] + cc;
            float l1 = h1[i] + cc;
            ss[0][i] += (idj == t32[0][i]) ? 0.0f : __expf(l0);
            ss[1][i] += (idj == t32[1][i]) ? 0.0f : __expf(l1);
        }

        __syncthreads();
    }

    // ---- per-row reduce over 32 col-lanes, write per-wave partial ----
    #pragma unroll
    for (int p = 0; p < 2; p++)
        #pragma unroll
        for (int i = 0; i < 16; i++) {
            float v = ss[p][i];
            v += __shfl_xor(v, 1);
            v += __shfl_xor(v, 2);
            v += __shfl_xor(v, 4);
            v += __shfl_xor(v, 8);
            v += __shfl_xor(v, 16);
            if (ln31 == 0) {
                int grow = m0 + wr * 64 + p * 32 + (i & 3) + 8 * (i >> 2) + 4 * half;
                ps[(size_t)grow * 8 + blockIdx.y * 2 + wc] = v;
            }
        }
}

// ---------------------------------------------------------------------------
// Kernel 4: finish = true logit (16 lanes/row, coalesced) + LSE combine.
// ---------------------------------------------------------------------------
__global__ __launch_bounds__(256) void finish_kernel(
    const float* __restrict__ x, const int* __restrict__ tgt,
    const float* __restrict__ emb, const float* __restrict__ bias,
    const unsigned* __restrict__ flag, const float* __restrict__ ps,
    float* __restrict__ out, float logr, float logns)
{
    const int gid = blockIdx.x * 256 + threadIdx.x;
    const int r   = gid >> 4;            // row
    const int l   = gid & 15;            // lane-in-row
    if (r >= BB) return;

    const int t = flag[0] ? tgt[2 * r] : tgt[r];

    const float4* xr = (const float4*)(x + (size_t)r * DD);
    const float4* wr = (const float4*)(emb + (size_t)t * DD);
    float4 xa = xr[l], xb = xr[l + 16];
    float4 wa = wr[l], wb = wr[l + 16];
    float d = xa.x*wa.x + xa.y*wa.y + xa.z*wa.z + xa.w*wa.w
            + xb.x*wb.x + xb.y*wb.y + xb.z*wb.z + xb.w*wb.w;
    d += __shfl_xor(d, 1);
    d += __shfl_xor(d, 2);
    d += __shfl_xor(d, 4);
    d += __shfl_xor(d, 8);

    if (l == 0) {
        float lp = log_q32((float)t, logr);
        float tl = d + bias[t] - (logns + lp);
        const float* p = ps + (size_t)r * 8;
        float S = ((p[0] + p[1]) + (p[2] + p[3])) + ((p[4] + p[5]) + (p[6] + p[7]));
        out[r] = logf(expf(tl - 60.0f) + S) + 60.0f - tl;
    }
}

// ---------------------------------------------------------------------------
extern "C" void kernel_launch(void* const* d_in, const int* in_sizes, int n_in,
                              void* d_out, int out_size, void* d_ws, size_t ws_size,
                              hipStream_t stream)
{
    const float* x    = (const float*)d_in[0];
    const int*   tgt  = (const int*)d_in[1];
    const float* emb  = (const float*)d_in[2];
    const float* bias = (const float*)d_in[3];
    float* out = (float*)d_out;

    char* w = (char*)d_ws;
    int*            ids  = (int*)(w + 0);                     //  32 KB
    float*          corr = (float*)(w + 32768);               //  32 KB
    unsigned*       flag = (unsigned*)(w + 65536);            //   4 B
    unsigned short* Xb   = (unsigned short*)(w + 131072);     //   4 MB
    unsigned short* Wh   = (unsigned short*)(w + 131072 + 4194304);  // 2 MB
    float*          ps   = (float*)(w + 131072 + 4194304 + 2097152); // 512 KB

    const float logr  = (float)log(1000001.0);
    const float logns = (float)log(8192.0);

    prep_kernel<<<dim3(BB * 16 / 256), dim3(256), 0, stream>>>(
        x, (const unsigned*)tgt, bias, Xb, ids, corr, flag, logr, logns);
    gather_kernel<<<dim3(NSAMP * 16 / 256), dim3(256), 0, stream>>>(
        emb, ids, Wh);
    gemm_kernel<<<dim3(BB / 128, 4), dim3(256), 0, stream>>>(
        Xb, tgt, flag, Wh, ids, corr, ps);
    finish_kernel<<<dim3(BB * 16 / 256), dim3(256), 0, stream>>>(
        x, tgt, emb, bias, flag, ps, out, logr, logns);
}